// Round 20
// baseline (3880.951 us; speedup 1.0000x reference)
//
#include <hip/hip_runtime.h>
#include <hip/hip_bf16.h>

typedef _Float16 f16x8 __attribute__((ext_vector_type(8)));
typedef float f32x4 __attribute__((ext_vector_type(4)));
typedef unsigned long long u64;

#define B_   128
#define T_   1024
#define H_   512
#define P_   32
#define HC_  16
#define MB_  32
#define NC_  8
#define NW_  4
#define SPIN_BOUND (1 << 20)

#define FRAG_MT 8192

// ws layout (bytes) — flags are 128B-STRIDED per producer (r20: un-packed;
// the r17 single-line packing made 32 producer stores serialize on one line)
#define WS_HEXHI  0ull
#define WS_HEXLO  524288ull
#define WS_FLAGR  1048576ull      // u32 [NC][32][32]: one 128B line per producer
#define WS_FLAGX  1081344ull      // u32 [4][32][32]
#define WS_XCC    1097728ull
#define WS_MECH   1098752ull
#define WS_PROBE  1099776ull
#define WS_ZEROL  1100800ull
#define WS_XT     1100800ull
#define WS_HLAST  2673664ull
#define WS_H1HI   2935808ull
#define WS_H1LO   137153536ull
#define WS_NEED_SMALL 137153536ull

#define MFMA(a, b, c) __builtin_amdgcn_mfma_f32_16x16x32_f16((a), (b), (c), 0, 0, 0)

// 8 coalesced dwordx4 loads (2 bases x 4 kt-chunks), ONE vmcnt(0).
#define LD8C(FLAGS, D, P0, P1)                                                  \
    asm volatile(                                                               \
        "global_load_dwordx4 %0, %8, off " FLAGS "\n\t"                         \
        "global_load_dwordx4 %1, %8, off offset:1024 " FLAGS "\n\t"             \
        "global_load_dwordx4 %2, %8, off offset:2048 " FLAGS "\n\t"             \
        "global_load_dwordx4 %3, %8, off offset:3072 " FLAGS "\n\t"             \
        "global_load_dwordx4 %4, %9, off " FLAGS "\n\t"                         \
        "global_load_dwordx4 %5, %9, off offset:1024 " FLAGS "\n\t"             \
        "global_load_dwordx4 %6, %9, off offset:2048 " FLAGS "\n\t"             \
        "global_load_dwordx4 %7, %9, off offset:3072 " FLAGS "\n\t"             \
        "s_waitcnt vmcnt(0)"                                                    \
        : "=&v"(D[0][0]), "=&v"(D[1][0]), "=&v"(D[2][0]), "=&v"(D[3][0]),       \
          "=&v"(D[0][1]), "=&v"(D[1][1]), "=&v"(D[2][1]), "=&v"(D[3][1])        \
        : "v"(P0), "v"(P1)                                                      \
        : "memory")

__device__ __forceinline__ unsigned ald4(const unsigned* p) {
    return __hip_atomic_load(p, __ATOMIC_RELAXED, __HIP_MEMORY_SCOPE_AGENT);
}
__device__ __forceinline__ void ast4(void* p, unsigned v) {
    __hip_atomic_store((unsigned*)p, v, __ATOMIC_RELAXED, __HIP_MEMORY_SCOPE_AGENT);
}
__device__ __forceinline__ void st4_plain(unsigned* p, unsigned v) {
    asm volatile("global_store_dword %0, %1, off" :: "v"(p), "v"(v) : "memory");
}
__device__ __forceinline__ unsigned ld4_sc1(const unsigned* p) {
    unsigned r;
    asm volatile("global_load_dword %0, %1, off sc1\n\ts_waitcnt vmcnt(0)"
                 : "=v"(r) : "v"(p) : "memory");
    return r;
}
__device__ __forceinline__ void st16_plain(void* p, f16x8 v) {
    asm volatile("global_store_dwordx4 %0, %1, off" :: "v"(p), "v"(v) : "memory");
}
__device__ __forceinline__ void st16_ic(void* p, f16x8 v) {
    asm volatile("global_store_dwordx4 %0, %1, off sc0 sc1" :: "v"(p), "v"(v) : "memory");
}
__device__ __forceinline__ unsigned short f16bits(_Float16 h) {
    union { _Float16 f; unsigned short s; } u; u.f = h; return u.s;
}
__device__ __forceinline__ void heat(unsigned v) {
    float a = (float)(v & 7u) + 1.0f;
    #pragma unroll
    for (int i = 0; i < 16; ++i)
        asm volatile("v_fmac_f32 %0, %1, %2" : "+v"(a) : "v"(1.000001f), "v"(a));
    asm volatile("" :: "v"(a));
}
// partial-buffer chunk swizzle (r18): deposits and transposed reads <=2-way.
__device__ __forceinline__ int swz(int cidx) { return cidx ^ ((cidx >> 3) & 7); }

__global__ __launch_bounds__(256)
void xt_kernel(const float* __restrict__ x, float* __restrict__ xT) {
    int idx = blockIdx.x * 256 + threadIdx.x;
    if (idx < B_ * T_ * 3) {
        int d = idx % 3, rest = idx / 3;
        int t = rest % T_, b = rest / T_;
        xT[((size_t)t * B_ + b) * 3 + d] = x[idx];
    }
}

// 256 blocks x 256 threads. Single-plane f16 exchange; weights hi/lo in LDS.
__global__ __launch_bounds__(256, 1)
void fused_slstm(const float* __restrict__ xT,
                 const float* __restrict__ W0, const float* __restrict__ R0,
                 const float* __restrict__ b0v,
                 const float* __restrict__ W1, const float* __restrict__ R1,
                 const float* __restrict__ b1v,
                 _Float16* __restrict__ hexFhi, _Float16* __restrict__ hexFlo,
                 unsigned* __restrict__ flagR, unsigned* __restrict__ flagX,
                 unsigned* __restrict__ xccbuf, unsigned* __restrict__ mech,
                 unsigned* __restrict__ probe,
                 _Float16* __restrict__ h1Fhi, _Float16* __restrict__ h1Flo,
                 float* __restrict__ hlast)
{
    constexpr int LDSH = 4 * 16 * 64 * 8;
    __shared__ _Float16 lds[2 * LDSH];
    __shared__ f32x4 bufA[512], bufB[512];
    __shared__ unsigned tbuf32[256];
    __shared__ int verdLds, mechLds, fastLds;

    const int tid  = threadIdx.x;
    const int lane = tid & 63;
    const int wid  = tid >> 6;
    const int l15  = lane & 15;
    const int l4   = lane >> 4;
    const int kg8  = l4 * 8;
    const int c    = blockIdx.x & 7;
    const int p    = blockIdx.x >> 3;
    const bool isL2 = (c >= 4);
    const int g    = c & 3;
    const int b0g  = g * MB_;

    const float* Rg  = isL2 ? R1 : R0;
    const float* bgp = isL2 ? b1v : b0v;

    // ---- stage weights (frag-major f16), wave wid -> gate q=wid ----
    {
        const int q = wid;
        const int grow = q * H_ + p * HC_ + l15;
        const float* rsrc = Rg + (size_t)grow * H_ + kg8;
        for (int kt = 0; kt < 16; ++kt) {
            const float* s = rsrc + kt * 32;
            _Float16* dhi = &lds[((q * 16 + kt) * 64 + lane) * 8];
            _Float16* dlo = dhi + LDSH;
            if (!isL2) {
                #pragma unroll
                for (int j = 0; j < 8; ++j) {
                    float v = s[j];
                    _Float16 h = (_Float16)v;
                    dhi[j] = h;
                    dlo[j] = (_Float16)(v - (float)h);   // R0_lo
                }
            } else {
                const float* ws2 = W1 + (size_t)grow * H_ + kt * 32 + kg8;
                #pragma unroll
                for (int j = 0; j < 8; ++j) {
                    dhi[j] = (_Float16)s[j];             // R1_hi
                    dlo[j] = (_Float16)ws2[j];           // W1_hi
                }
            }
        }
    }

    // ==== Phase 1: XCC mapping verdict ====
    {
        unsigned myxcc;
        asm volatile("s_getreg_b32 %0, hwreg(20, 0, 32)" : "=s"(myxcc));
        if (tid == 0) ast4(xccbuf + blockIdx.x, 0x100u | (myxcc & 0xFFu));
        if (wid == 0) {
            const unsigned* xp = xccbuf + ((lane & 31) * 8 + c);
            unsigned v = 0;
            int ok = 0;
            for (int it = 0; it < SPIN_BOUND; ++it) {
                v = ald4(xp);
                if (__ballot(v >= 0x100u) == ~0ull) { ok = 1; break; }
                __builtin_amdgcn_s_sleep(2);
            }
            unsigned ref = (unsigned)__shfl((int)v, 0);
            bool alleq = ok && (__ballot((v & 0xFFu) == (ref & 0xFFu)) == ~0ull);
            unsigned o = 0;
            int ok2 = 0;
            const unsigned* op = xccbuf + (c ^ 1);
            for (int it = 0; it < SPIN_BOUND; ++it) {
                o = ald4(op);
                if (o >= 0x100u) { ok2 = 1; break; }
                __builtin_amdgcn_s_sleep(2);
            }
            bool cand = alleq && ok2 && ((o & 0xFFu) != (ref & 0xFFu));
            if (lane == 0) verdLds = cand ? 1 : 0;
        }
    }
    __syncthreads();
    const bool candFast = (verdLds != 0);

    // ==== Phase 2: mechanism probe ====
    if (candFast && p == 0 && tid == 0) {
        for (unsigned k = 1; k <= 3; ++k) {
            st4_plain(probe + c * 32, k);
            asm volatile("s_waitcnt vmcnt(0)" ::: "memory");
            for (int s = 0; s < 32; ++s) __builtin_amdgcn_s_sleep(127);
        }
    }
    if (candFast && wid == 0) {
        unsigned first = 0xFFFFFFFFu;
        int got = 0;
        for (int it = 0; it < (1 << 16); ++it) {
            unsigned v = ld4_sc1(probe + c * 32);
            if (first == 0xFFFFFFFFu) first = v;
            if (v >= 3u) { got = 1; break; }
            __builtin_amdgcn_s_sleep(2);
        }
        if (p != 0 && first >= 3u) got = 0;
        if (lane == 0) mechLds = got;
    }
    __syncthreads();
    const int saw = candFast ? mechLds : 0;

    // ==== Phase 3: consensus ====
    if (tid == 0) ast4(mech + blockIdx.x, 0x100u | (unsigned)(saw & 1));
    if (wid == 0) {
        const unsigned* mp = mech + ((lane & 31) * 8 + c);
        unsigned v = 0;
        int ok = 0;
        for (int it = 0; it < SPIN_BOUND; ++it) {
            v = ald4(mp);
            if (__ballot(v >= 0x100u) == ~0ull) { ok = 1; break; }
            __builtin_amdgcn_s_sleep(2);
        }
        bool allsaw = ok && (__ballot((v & 1u) != 0u) == ~0ull);
        if (lane == 0) fastLds = (candFast && allsaw) ? 1 : 0;
    }

    // ---- per-thread state geometry (all 256 threads: 2 elements each) ----
    const int colIdx = tid & 15;
    const int col    = p * HC_ + colIdx;
    const int row0   = tid >> 4;
    float bb[4], w0r[4][3];
    #pragma unroll
    for (int q = 0; q < 4; ++q) bb[q] = bgp[q * H_ + col];
    if (!isL2) {
        #pragma unroll
        for (int q = 0; q < 4; ++q)
            #pragma unroll
            for (int d = 0; d < 3; ++d)
                w0r[q][d] = W0[(size_t)(q * H_ + col) * 3 + d];
    }
    float cS[2] = {0.f, 0.f}, nS[2] = {0.f, 0.f}, mS[2] = {0.f, 0.f};

    const int kt0 = wid * 4;
    int dead = 0;

    __syncthreads();
    const bool fast = (fastLds != 0);

    for (int t = 0; t < T_; ++t) {
        float xa[2][3];
        if (!isL2) {
            #pragma unroll
            for (int h = 0; h < 2; ++h) {
                const float* xp = xT + ((size_t)t * B_ + b0g + row0 + h * 16) * 3;
                xa[h][0] = xp[0]; xa[h][1] = xp[1]; xa[h][2] = xp[2];
            }
        }

        f32x4 acc[2][4];
        #pragma unroll
        for (int mt = 0; mt < 2; ++mt)
            #pragma unroll
            for (int q = 0; q < 4; ++q) { f32x4 z = {0.f,0.f,0.f,0.f}; acc[mt][q] = z; }

        // ---- L2 feed-forward: poll flagX (strided lines), 8 h1F loads + 16 MFMA ----
        if (isL2) {
            if (!dead) {
                const unsigned* fx = flagX + ((size_t)(g * 32 + (lane & 31)) << 5);
                int it = 0;
                for (;;) {
                    unsigned v = fast ? ld4_sc1(fx) : ald4(fx);
                    if (__ballot(v >= (unsigned)(t + 1)) == ~0ull) break;
                    if (++it > SPIN_BOUND) { dead = 1; break; }
                    heat(v);
                }
            }
            asm volatile("" ::: "memory");
            f16x8 xh[4][2];
            const size_t tb = (((size_t)t * 4 + g) * 2) * FRAG_MT + kt0 * 512 + lane * 8;
            const _Float16* q0 = h1Fhi + tb;
            const _Float16* q1 = h1Fhi + tb + FRAG_MT;
            LD8C("sc0 sc1", xh, q0, q1);
            #pragma unroll
            for (int k = 0; k < 4; ++k)
                #pragma unroll
                for (int q = 0; q < 4; ++q) {
                    f16x8 w = *(const f16x8*)&lds[LDSH + ((q * 16 + kt0 + k) * 64 + lane) * 8];
                    acc[0][q] = MFMA(xh[k][0], w, acc[0][q]);
                    acc[1][q] = MFMA(xh[k][1], w, acc[1][q]);
                }
        }

        // ---- recurrent wait: strided-line poll (one line per producer) ----
        if (t > 0 && !dead) {
            const unsigned* fr = flagR + ((size_t)(c * 32 + (lane & 31)) << 5);
            int it = 0;
            for (;;) {
                unsigned v = fast ? ld4_sc1(fr) : ald4(fr);
                if (__ballot(v >= (unsigned)t) == ~0ull) break;
                if (++it > SPIN_BOUND) { dead = 1; break; }
                heat(v);
            }
            asm volatile("" ::: "memory");
        }

        // ---- recurrent A-frags (8 coalesced loads) + MFMAs ----
        f16x8 ah[4][2];
        {
            const size_t hb = (((size_t)(t & 1) * NC_ + c) * 2) * FRAG_MT + kt0 * 512 + lane * 8;
            const _Float16* ph0 = hexFhi + hb;
            const _Float16* ph1 = hexFhi + hb + FRAG_MT;
            if (fast) { LD8C("sc1", ah, ph0, ph1); }
            else      { LD8C("sc0 sc1", ah, ph0, ph1); }
        }
        #pragma unroll
        for (int k = 0; k < 4; ++k)
            #pragma unroll
            for (int q = 0; q < 4; ++q) {
                f16x8 rh = *(const f16x8*)&lds[((q * 16 + kt0 + k) * 64 + lane) * 8];
                acc[0][q] = MFMA(ah[k][0], rh, acc[0][q]);
                acc[1][q] = MFMA(ah[k][1], rh, acc[1][q]);
                if (!isL2) {      // h x R0_lo (weight-precision compensation)
                    f16x8 rlo = *(const f16x8*)&lds[LDSH + ((q * 16 + kt0 + k) * 64 + lane) * 8];
                    acc[0][q] = MFMA(ah[k][0], rlo, acc[0][q]);
                    acc[1][q] = MFMA(ah[k][1], rlo, acc[1][q]);
                }
            }

        // ---- pairwise tree reduce (swizzled, atomic-free) ----
        if (wid == 1) {
            #pragma unroll
            for (int mt = 0; mt < 2; ++mt)
                #pragma unroll
                for (int q = 0; q < 4; ++q)
                    bufA[swz((mt * 4 + q) * 64 + lane)] = acc[mt][q];
        } else if (wid == 3) {
            #pragma unroll
            for (int mt = 0; mt < 2; ++mt)
                #pragma unroll
                for (int q = 0; q < 4; ++q)
                    bufB[swz((mt * 4 + q) * 64 + lane)] = acc[mt][q];
        }
        __syncthreads();                       // bar1
        if (wid == 2) {
            #pragma unroll
            for (int mt = 0; mt < 2; ++mt)
                #pragma unroll
                for (int q = 0; q < 4; ++q) {
                    const int s = swz((mt * 4 + q) * 64 + lane);
                    f32x4 v = bufA[s]; v += acc[mt][q]; bufA[s] = v;
                }
        } else if (wid == 0) {
            #pragma unroll
            for (int mt = 0; mt < 2; ++mt)
                #pragma unroll
                for (int q = 0; q < 4; ++q) {
                    const int s = swz((mt * 4 + q) * 64 + lane);
                    f32x4 v = bufB[s]; v += acc[mt][q]; bufB[s] = v;
                }
        }
        __syncthreads();                       // bar2

        // ---- distributed state phase: 256 threads x 2 elements ----
        const float* fA = (const float*)bufA;
        const float* fB = (const float*)bufB;
        unsigned pk[2];
        #pragma unroll
        for (int h = 0; h < 2; ++h) {
            float gq[4];
            #pragma unroll
            for (int q = 0; q < 4; ++q) {
                const int cidx = (h * 4 + q) * 64 + (row0 >> 2) * 16 + colIdx;
                const int w = swz(cidx) * 4 + (row0 & 3);
                float e = fA[w] + fB[w] + bb[q];
                if (!isL2)
                    e += w0r[q][0]*xa[h][0] + w0r[q][1]*xa[h][1] + w0r[q][2]*xa[h][2];
                gq[q] = e;
            }
            float iv = gq[0], fv = gq[1], zv = gq[2], ov = gq[3];
            float fm = fv + mS[h];
            float mn = fmaxf(fm, iv);
            float ig = __expf(iv - mn);
            float fg = __expf(fm - mn);
            float zc = fminf(fmaxf(zv, -15.f), 15.f);
            float e2 = __expf(2.f * zc);
            float th = (e2 - 1.f) / (e2 + 1.f);
            cS[h] = fg * cS[h] + ig * th;
            nS[h] = fg * nS[h] + ig;
            mS[h] = mn;
            float sg = 1.f / (1.f + __expf(-ov));
            float hv = sg * cS[h] / fmaxf(nS[h], 1e-6f);

            if (isL2 && t == T_ - 1)
                hlast[(size_t)(b0g + row0 + h * 16) * H_ + col] = hv;

            unsigned self = (unsigned)f16bits((_Float16)hv);
            unsigned part = (unsigned)__shfl_xor((int)(self << 16), 1) >> 16;
            pk[h] = (self & 0xffffu) | ((unsigned)part << 16);
        }

        // ---- stage packed pairs into tbuf [h][fl4i][row][cj] ----
        if (!(colIdx & 1)) {
            const int fl4i = colIdx >> 3;
            const int cj   = (colIdx & 7) >> 1;
            #pragma unroll
            for (int h = 0; h < 2; ++h)
                tbuf32[((h * 2 + fl4i) * 16 + row0) * 4 + cj] = pk[h];
        }
        __syncthreads();                       // bar3

        // ---- wave0: dense frag stores + drain + flags (own 128B line each) ----
        if (wid == 0) {
            const f16x8* tv = (const f16x8*)tbuf32;
            f16x8 vh = tv[lane & 63];
            const int mt   = lane >> 5;
            const int fl4i = (lane >> 4) & 1;
            const int row  = lane & 15;
            const int flg  = row + 16 * ((p & 1) * 2 + fl4i);
            const size_t tail = (size_t)(p >> 1) * 512 + (size_t)flg * 8;
            const size_t feh = (((size_t)((t + 1) & 1) * NC_ + c) * 2 + mt) * FRAG_MT + tail;
            if (fast) st16_plain(hexFhi + feh, vh);
            else      st16_ic(hexFhi + feh, vh);
            asm volatile("s_waitcnt vmcnt(0)" ::: "memory");
            if (lane == 0) {
                unsigned* frp = flagR + ((size_t)(c * 32 + p) << 5);
                if (fast) st4_plain(frp, (unsigned)(t + 1));
                else      ast4(frp, (unsigned)(t + 1));
                if (!isL2) ast4(flagX + ((size_t)(c * 32 + p) << 5), (unsigned)t); // lagged
            }
            if (!isL2) {                 // fire-and-forget; next step's vmcnt drains
                const size_t fex = (((size_t)t * 4 + g) * 2 + mt) * FRAG_MT + tail;
                st16_ic(h1Fhi + fex, vh);
            }
        }
    }

    // ---- post-loop (L1): drain h1F tail, publish final flagX ----
    if (!isL2) {
        asm volatile("s_waitcnt vmcnt(0)" ::: "memory");
        __syncthreads();
        if (tid == 0) ast4(flagX + ((size_t)(c * 32 + p) << 5), (unsigned)(T_ + 1));
    }
}

#define OUT_ 26
__global__ __launch_bounds__(64)
void fc_kernel(const float* __restrict__ hlast, const float* __restrict__ fcw,
               const float* __restrict__ fcb, float* __restrict__ out)
{
    int b = blockIdx.x, oo = threadIdx.x;
    if (oo < OUT_) {
        const float4* hv = reinterpret_cast<const float4*>(hlast + (size_t)b * H_);
        const float4* wv = reinterpret_cast<const float4*>(fcw + (size_t)oo * H_);
        float s = fcb[oo];
        #pragma unroll 4
        for (int k = 0; k < H_ / 4; ++k) {
            float4 h4 = hv[k], w4 = wv[k];
            s += h4.x * w4.x + h4.y * w4.y + h4.z * w4.z + h4.w * w4.w;
        }
        out[(size_t)b * OUT_ + oo] = s;
    }
}

extern "C" void kernel_launch(void* const* d_in, const int* in_sizes, int n_in,
                              void* d_out, int out_size, void* d_ws, size_t ws_size,
                              hipStream_t stream) {
    const float* x   = (const float*)d_in[0];
    const float* W0  = (const float*)d_in[1];
    const float* R0  = (const float*)d_in[2];
    const float* b0  = (const float*)d_in[3];
    const float* W1  = (const float*)d_in[4];
    const float* R1  = (const float*)d_in[5];
    const float* b1  = (const float*)d_in[6];
    const float* fcw = (const float*)d_in[7];
    const float* fcb = (const float*)d_in[8];
    float* out = (float*)d_out;

    if (ws_size < WS_NEED_SMALL) return;

    char* ws = (char*)d_ws;
    _Float16* hexFhi = (_Float16*)(ws + WS_HEXHI);
    _Float16* hexFlo = (_Float16*)(ws + WS_HEXLO);
    unsigned* flagR  = (unsigned*)(ws + WS_FLAGR);
    unsigned* flagX  = (unsigned*)(ws + WS_FLAGX);
    unsigned* xccb   = (unsigned*)(ws + WS_XCC);
    unsigned* mech   = (unsigned*)(ws + WS_MECH);
    unsigned* probe  = (unsigned*)(ws + WS_PROBE);
    float*    xTp    = (float*)(ws + WS_XT);
    float*    hlast  = (float*)(ws + WS_HLAST);
    _Float16* h1Fhi  = (_Float16*)(ws + WS_H1HI);
    _Float16* h1Flo  = (_Float16*)(ws + WS_H1LO);

    hipMemsetAsync(ws, 0, WS_ZEROL, stream);
    xt_kernel<<<(B_ * T_ * 3 + 255) / 256, 256, 0, stream>>>(x, xTp);
    fused_slstm<<<NC_ * P_, NW_ * 64, 0, stream>>>(xTp, W0, R0, b0, W1, R1, b1,
                                                   hexFhi, hexFlo, flagR, flagX,
                                                   xccb, mech, probe,
                                                   h1Fhi, h1Flo, hlast);
    fc_kernel<<<B_, 64, 0, stream>>>(hlast, fcw, fcb, out);
}